// Round 16
// baseline (2271.914 us; speedup 1.0000x reference)
//
#include <hip/hip_runtime.h>
#include <hip/hip_fp16.h>

typedef unsigned long long u64;
typedef __attribute__((ext_vector_type(8))) short bf16x8;
typedef __attribute__((ext_vector_type(4))) float f32x4;

#define SEG_N     8192
#define NSEG      2
#define M_PER_SEG 2048
#define M_TOTAL   4096
#define CFEAT     64
#define COUT      128
#define NSAMPLE   16

#define FPS_WGS_PER_SEG 16
#define FPS_THREADS     512
#define FPS_WAVES       8
#define SLOT_STRIDE     16

// d_out layout (floats): new_xyz | new_feat | new_offset | new_vel
#define OUT_XYZ   0
#define OUT_FEAT  12288
#define OUT_OFF   536576
#define OUT_VEL   536578

// d_ws layout (bytes)
#define WS_CAND 0
#define WS_FPS  512
#define WS_KNN  16896
#define WS_SQ   (1<<19)
#define WS_D2   (1<<20)
#define D2_SEG8 ((size_t)SEG_N * SEG_N)       // 67 MB per segment (u8)

#define AG  __HIP_MEMORY_SCOPE_AGENT
#define RLX __ATOMIC_RELAXED

#define REP16(M) M(0) M(1) M(2) M(3) M(4) M(5) M(6) M(7) \
                 M(8) M(9) M(10) M(11) M(12) M(13) M(14) M(15)
#define REP16_EO(E,O) E(0) O(1) E(2) O(3) E(4) O(5) E(6) O(7) \
                      E(8) O(9) E(10) O(11) E(12) O(13) E(14) O(15)

__device__ __forceinline__ unsigned pk2(float a, float b) {
  __half2 h = __floats2half2_rn(a, b);
  unsigned u; __builtin_memcpy(&u, &h, 4); return u;
}
__device__ __forceinline__ float2 up2(unsigned u) {
  __half2 h; __builtin_memcpy(&h, &u, 4);
  return __half22float2(h);
}

template<int CTRL, int RM>
__device__ __forceinline__ unsigned dppmax(unsigned c) {
  int t = __builtin_amdgcn_update_dpp(0, (int)c, CTRL, RM, 0xF, true);
  unsigned u = (unsigned)t;
  return c > u ? c : u;
}

__device__ __forceinline__ short f2bf(float v) {
  return (short)((__float_as_uint(v) + 0x8000u) >> 16);   // RN-ish bf16
}

// ===========================================================================
// FAST PATH: u8 d^2 matrix via MFMA-bf16 gram; FPS with runner-up prefetch.
// ===========================================================================

__global__ __launch_bounds__(256)
void norm_kernel(const float* __restrict__ xyz, const float* __restrict__ feat,
                 float* __restrict__ sq)
{
  int i = blockIdx.x * 256 + threadIdx.x;
  if (i >= NSEG * SEG_N) return;
  float a0 = xyz[(size_t)i*3+0], a1 = xyz[(size_t)i*3+1], a2 = xyz[(size_t)i*3+2];
  float acc = a0*a0 + a1*a1 + a2*a2;
  const float4* fr = (const float4*)(feat + (size_t)i * CFEAT);
  #pragma unroll
  for (int k = 0; k < 16; ++k) {
    float4 v = fr[k];
    acc += v.x*v.x + v.y*v.y + v.z*v.z + v.w*v.w;
  }
  sq[i] = acc;
}

// MFMA bf16 gram: 128q x 128p u8 d^2 tile per WG. K = 96 (xyz|feat|zeros).
#define GKS 104
__global__ __launch_bounds__(256)
void gram_mfma_kernel(const float* __restrict__ xyz, const float* __restrict__ feat,
                      const float* __restrict__ sq, unsigned char* __restrict__ d2m)
{
  __shared__ __align__(16) short Xq[128][GKS];
  __shared__ __align__(16) short Xp[128][GKS];
  __shared__ float sqs[128], sps[128];

  const int b   = blockIdx.x;
  const int s   = b >> 12;
  const int rem = b & 4095;
  const int tq  = rem >> 6;
  const int tp  = rem & 63;
  const int q0  = tq * 128, p0 = tp * 128;
  const int tid = threadIdx.x;
  unsigned char* d2seg = d2m + (size_t)s * D2_SEG8;

  for (int e = tid; e < 128 * 96; e += 256) {
    int r = e / 96, c = e - r * 96;
    size_t gq = (size_t)(s * SEG_N + q0 + r);
    size_t gp = (size_t)(s * SEG_N + p0 + r);
    float vq = 0.f, vp = 0.f;
    if (c < 3)        { vq = xyz[gq*3 + c];          vp = xyz[gp*3 + c]; }
    else if (c < 67)  { vq = feat[gq*CFEAT + (c-3)]; vp = feat[gp*CFEAT + (c-3)]; }
    Xq[r][c] = f2bf(vq);
    Xp[r][c] = f2bf(vp);
  }
  if (tid < 128)      sqs[tid] = sq[s * SEG_N + q0 + tid];
  else                sps[tid - 128] = sq[s * SEG_N + p0 + (tid - 128)];
  __syncthreads();

  const int lane = tid & 63;
  const int wv   = tid >> 6;
  const int wr   = wv >> 1, wc = wv & 1;
  const int lrow = lane & 15;
  const int kgr  = (lane >> 4) * 8;

  f32x4 acc[4][4];
  #pragma unroll
  for (int i = 0; i < 4; ++i)
    #pragma unroll
    for (int j = 0; j < 4; ++j) acc[i][j] = (f32x4){0.f,0.f,0.f,0.f};

  #pragma unroll
  for (int ch = 0; ch < 3; ++ch) {
    bf16x8 af[4], bf[4];
    #pragma unroll
    for (int i = 0; i < 4; ++i)
      af[i] = *(const bf16x8*)&Xq[wr*64 + i*16 + lrow][ch*32 + kgr];
    #pragma unroll
    for (int j = 0; j < 4; ++j)
      bf[j] = *(const bf16x8*)&Xp[wc*64 + j*16 + lrow][ch*32 + kgr];
    #pragma unroll
    for (int i = 0; i < 4; ++i)
      #pragma unroll
      for (int j = 0; j < 4; ++j)
        acc[i][j] = __builtin_amdgcn_mfma_f32_16x16x32_bf16(af[i], bf[j],
                                                            acc[i][j], 0, 0, 0);
  }
  __syncthreads();

  unsigned char* ob = (unsigned char*)&Xq[0][0];
  #pragma unroll
  for (int i = 0; i < 4; ++i) {
    #pragma unroll
    for (int j = 0; j < 4; ++j) {
      #pragma unroll
      for (int reg = 0; reg < 4; ++reg) {
        int r  = wr*64 + i*16 + (lane >> 4)*4 + reg;
        int cl = wc*64 + j*16 + (lane & 15);
        float d2 = sqs[r] + sps[cl] - 2.f * acc[i][j][reg];
        unsigned o;
        if (q0 + r == p0 + cl) o = 0u;
        else {
          d2 = fmaxf(d2, 0.f);
          o = __float2uint_rn(fminf(d2, 255.f));
        }
        ob[(r << 7) + cl] = (unsigned char)o;
      }
    }
  }
  __syncthreads();

  const unsigned* obu = (const unsigned*)ob;
  for (int e = tid; e < 4096; e += 256) {
    int r = e >> 5, cw = e & 31;
    *(unsigned*)&d2seg[((size_t)(q0 + r) << 13) + p0 + cw*4] = obu[e];
  }
}

// FPS with runner-up prefetch: per step, besides picking the winner q, also
// extract the 2nd-max of the 16 funnel slots (mask winner, 4 DPP) = predicted
// next query; always prefetch its row-slice. Next step: if q == pred, use the
// prefetched regs (uniform scalar branch, NO dependent load); else load.
// FPS theorem: if the runner-up's D wasn't reduced by this step's update, it
// IS the next argmax -- so the prediction hits often. Selection unchanged.
__global__ __launch_bounds__(1024)
void fps_fast8_kernel(const unsigned char* __restrict__ d2m,
                      int* __restrict__ fps_idx)
{
  __shared__ unsigned wslot[2][16];

  const int tid  = threadIdx.x;
  const int lane = tid & 63;
  const int wv   = tid >> 6;
  const int s    = blockIdx.x;
  const int p0   = tid * 8;
  const unsigned idx0 = 8191 - p0;
  const unsigned char* base_s = d2m + (size_t)s * D2_SEG8;

  unsigned D0=255u,D1=255u,D2v=255u,D3=255u,D4=255u,D5=255u,D6=255u,D7=255u;

  if (tid == 0) fps_idx[s * M_PER_SEG] = 0;

  uint2 cur = *(const uint2*)(base_s + p0);   // row of q0 = 0
  uint2 Pf  = cur;                            // prefetch regs (invalid yet)
  int pred = -1;

  for (int t = 1; t < M_PER_SEG; ++t) {
    unsigned a = cur.x, b = cur.y;
    D0 = min(D0,  a        & 255u);
    D1 = min(D1, (a >>  8) & 255u);
    D2v= min(D2v,(a >> 16) & 255u);
    D3 = min(D3,  a >> 24);
    D4 = min(D4,  b        & 255u);
    D5 = min(D5, (b >>  8) & 255u);
    D6 = min(D6, (b >> 16) & 255u);
    D7 = min(D7,  b >> 24);

    unsigned c = (D0 << 13) | idx0;
    c = max(c, (D1 << 13) | (idx0 - 1u));
    c = max(c, (D2v<< 13) | (idx0 - 2u));
    c = max(c, (D3 << 13) | (idx0 - 3u));
    c = max(c, (D4 << 13) | (idx0 - 4u));
    c = max(c, (D5 << 13) | (idx0 - 5u));
    c = max(c, (D6 << 13) | (idx0 - 6u));
    c = max(c, (D7 << 13) | (idx0 - 7u));

    c = dppmax<0x111, 0xF>(c);
    c = dppmax<0x112, 0xF>(c);
    c = dppmax<0x114, 0xF>(c);
    c = dppmax<0x118, 0xF>(c);
    c = dppmax<0x142, 0xA>(c);
    c = dppmax<0x143, 0xC>(c);
    unsigned wmax = (unsigned)__builtin_amdgcn_readlane((int)c, 63);

    if (lane == 0) wslot[t & 1][wv] = wmax;
    __syncthreads();

    unsigned v = wslot[t & 1][lane & 15];
    unsigned m = v;
    m = dppmax<0x111, 0xF>(m);
    m = dppmax<0x112, 0xF>(m);
    m = dppmax<0x114, 0xF>(m);
    m = dppmax<0x118, 0xF>(m);
    unsigned gmax = (unsigned)__builtin_amdgcn_readlane((int)m, 15);

    // runner-up among funnel slots (slot values are globally unique)
    unsigned v2 = (v == gmax) ? 0u : v;
    v2 = dppmax<0x111, 0xF>(v2);
    v2 = dppmax<0x112, 0xF>(v2);
    v2 = dppmax<0x114, 0xF>(v2);
    v2 = dppmax<0x118, 0xF>(v2);
    unsigned g2 = (unsigned)__builtin_amdgcn_readlane((int)v2, 15);

    int q  = 8191 - (int)(gmax & 0x1FFFu);
    int rn = 8191 - (int)(g2 & 0x1FFFu);
    if (tid == 0) fps_idx[s * M_PER_SEG + t] = q;

    if (q == pred) {
      cur = Pf;                                  // prefetch hit: no load
    } else {
      cur = *(const uint2*)(base_s + ((size_t)q << 13) + p0);
    }
    Pf   = *(const uint2*)(base_s + ((size_t)rn << 13) + p0);
    pred = rn;
  }
}

// ===========================================================================
// FALLBACK: distributed MALL-sync FPS, fp16-packed named registers.
// ===========================================================================
__global__ __attribute__((amdgpu_waves_per_eu(2, 2)))
__launch_bounds__(FPS_THREADS)
void fps_kernel(const float* __restrict__ xyz, const float* __restrict__ feat,
                u64* __restrict__ cand, int* __restrict__ fps_idx)
{
#pragma clang fp contract(off)
  __shared__ u64 wslot[FPS_WAVES];
  __shared__ int qidx_sh;

  const int tid  = threadIdx.x;
  const int lane = tid & 63;
  const int wv   = tid >> 6;
  const int s    = blockIdx.x >> 4;
  const int wg   = blockIdx.x & 15;
  const int pl   = wg * FPS_THREADS + tid;
  const size_t gr = (size_t)(s * SEG_N + pl);

  float px, py, pz;
#define DECLP(k) uint2 pp##k;
  REP16(DECLP)
  px = xyz[gr*3+0]; py = xyz[gr*3+1]; pz = xyz[gr*3+2];
  {
    const float4* fr = (const float4*)(feat + gr * CFEAT);
#define LOADP(k) { float4 v = fr[k]; pp##k.x = pk2(v.x, v.y); pp##k.y = pk2(v.z, v.w); }
    REP16(LOADP)
  }

  float qx, qy, qz;
#define DECLQ(k) float4 qf##k;
  REP16(DECLQ)
#define LOADQ1(k) qf##k = frq[k];
#define LOAD_Q(qb) { \
    qx = xyz[(qb)*3+0]; qy = xyz[(qb)*3+1]; qz = xyz[(qb)*3+2]; \
    const float4* frq = (const float4*)(feat + (qb) * CFEAT); \
    REP16(LOADQ1) }

  LOAD_Q((size_t)(s * SEG_N))
  if (tid == 0 && wg == 0) fps_idx[s * M_PER_SEG] = 0;

  float D = 1e10f;

  for (int t = 1; t < M_PER_SEG; ++t) {
    float r0=0.f, r1=0.f, r2=0.f, r3=0.f, r4=0.f, r5=0.f, r6=0.f, r7=0.f;
    {
      float tt;
      tt = px - qx; r0 += tt*tt;
      tt = py - qy; r1 += tt*tt;
      tt = pz - qz; r2 += tt*tt;
    }
#define DE(k) { float2 ab = up2(pp##k.x), cd = up2(pp##k.y); \
                float t0 = ab.x - qf##k.x; r3 += t0*t0; \
                float t1 = ab.y - qf##k.y; r4 += t1*t1; \
                float t2 = cd.x - qf##k.z; r5 += t2*t2; \
                float t3 = cd.y - qf##k.w; r6 += t3*t3; }
#define DO(k) { float2 ab = up2(pp##k.x), cd = up2(pp##k.y); \
                float t0 = ab.x - qf##k.x; r7 += t0*t0; \
                float t1 = ab.y - qf##k.y; r0 += t1*t1; \
                float t2 = cd.x - qf##k.z; r1 += t2*t2; \
                float t3 = cd.y - qf##k.w; r2 += t3*t3; }
    REP16_EO(DE, DO)
    float a = ((r0+r1)+(r2+r3)) + ((r4+r5)+(r6+r7));
    D = fminf(D, a);

    float bd = D; int bi = pl;
    #pragma unroll
    for (int off = 32; off >= 1; off >>= 1) {
      float od = __shfl_xor(bd, off);
      int   oi = __shfl_xor(bi, off);
      if (od > bd || (od == bd && oi < bi)) { bd = od; bi = oi; }
    }
    if (lane == 0)
      wslot[wv] = ((u64)__float_as_uint(bd) << 13) | (u64)(unsigned)(8191 - bi);
    __syncthreads();

    if (wv == 0) {
      u64 w = (lane < FPS_WAVES) ? wslot[lane] : 0ULL;
      #pragma unroll
      for (int off = 4; off >= 1; off >>= 1) {
        u64 o = __shfl_xor(w, off, 8);
        if (o > w) w = o;
      }
      u64* base = &cand[(((unsigned)t & 1u) * NSEG + s) * SLOT_STRIDE];
      if (lane == 0)
        __hip_atomic_store(&base[wg], ((u64)(unsigned)t << 45) | w, RLX, AG);

      u64 v = 0;
      if (lane < FPS_WGS_PER_SEG) {
        v = __hip_atomic_load(&base[lane], RLX, AG);
        while ((unsigned)(v >> 45) != (unsigned)t) {
          __builtin_amdgcn_s_sleep(1);
          v = __hip_atomic_load(&base[lane], RLX, AG);
        }
      }
      #pragma unroll
      for (int off = 8; off >= 1; off >>= 1) {
        u64 o = __shfl_xor(v, off, 16);
        if (o > v) v = o;
      }
      int qi = 8191 - (int)(v & 0x1FFFu);
      if (lane == 0) {
        qidx_sh = qi;
        if (wg == 0) fps_idx[s * M_PER_SEG + t] = qi;
      }
    }
    __syncthreads();

    LOAD_Q((size_t)(s * SEG_N + qidx_sh))
  }
}

// ---------------------------------------------------------------------------
__global__ void gather_kernel(const float* __restrict__ xyz, const float* __restrict__ vel,
                              const int* __restrict__ fps_idx, float* __restrict__ out)
{
  int i = blockIdx.x * 256 + threadIdx.x;
  if (i >= M_TOTAL) return;
  int s = i >> 11, r = i & 2047;
  int g = s * SEG_N + (fps_idx[s * M_PER_SEG + r] & 8191);
  out[OUT_XYZ + i*3 + 0] = xyz[(size_t)g*3 + 0];
  out[OUT_XYZ + i*3 + 1] = xyz[(size_t)g*3 + 1];
  out[OUT_XYZ + i*3 + 2] = xyz[(size_t)g*3 + 2];
  out[OUT_VEL + i*3 + 0] = vel[(size_t)g*3 + 0];
  out[OUT_VEL + i*3 + 1] = vel[(size_t)g*3 + 1];
  out[OUT_VEL + i*3 + 2] = vel[(size_t)g*3 + 2];
  if (i == 0) { out[OUT_OFF] = 2048.0f; out[OUT_OFF + 1] = 4096.0f; }
}

// ---------------------------------------------------------------------------
#define KNN_TILE 1024
__global__ __launch_bounds__(256)
void knn_kernel(const float* __restrict__ xyz, const float* __restrict__ out,
                int* __restrict__ knn)
{
  __shared__ float px[KNN_TILE], py[KNN_TILE], pz[KNN_TILE];
  __shared__ float ldK[16][16][16];
  __shared__ float Tq[16];
  __shared__ float dbuf[16][24];
  __shared__ int   cbuf[16][24];
  __shared__ int   cnt[16];

  const int tid = threadIdx.x;
  const int ql = tid >> 4, j = tid & 15;
  const int qg = blockIdx.x * 16 + ql;
  const int s  = qg >> 11;
  const float qx = out[OUT_XYZ + qg*3 + 0];
  const float qy = out[OUT_XYZ + qg*3 + 1];
  const float qz = out[OUT_XYZ + qg*3 + 2];
  const float sq = qx*qx + qy*qy + qz*qz;

  float K[16];
  #pragma unroll
  for (int r = 0; r < 16; ++r) K[r] = 3.4e38f;

  for (int tile = 0; tile < SEG_N / KNN_TILE; ++tile) {
    __syncthreads();
    for (int u = tid; u < KNN_TILE; u += 256) {
      size_t g = (size_t)(s * SEG_N + tile * KNN_TILE + u);
      px[u] = xyz[g*3+0]; py[u] = xyz[g*3+1]; pz[u] = xyz[g*3+2];
    }
    __syncthreads();
    #pragma unroll 4
    for (int i = 0; i < KNN_TILE / 16; ++i) {
      int c = i * 16 + j;
      float x = px[c], y = py[c], z = pz[c];
      float sp  = x*x + y*y + z*z;
      float dot = qx*x + qy*y + qz*z;
      float d2  = (sq + sp) - 2.0f * dot;
      #pragma unroll
      for (int r = 15; r >= 1; --r)
        K[r] = fminf(fmaxf(d2, K[r-1]), K[r]);
      K[0] = fminf(K[0], d2);
    }
  }
  #pragma unroll
  for (int r = 0; r < 16; ++r) ldK[ql][j][r] = K[r];
  __syncthreads();

  {
    int head = 0;
    float T = 3.4e38f;
    for (int r = 0; r < 16; ++r) {
      float val = (head < 16) ? ldK[ql][j][head] : 3.4e38f;
      float mv = val; int ml = j;
      #pragma unroll
      for (int off = 8; off >= 1; off >>= 1) {
        float ov = __shfl_xor(mv, off, 16);
        int   ol = __shfl_xor(ml, off, 16);
        if (ov < mv || (ov == mv && ol < ml)) { mv = ov; ml = ol; }
      }
      if (j == ml) head++;
      T = mv;
    }
    if (j == 0) { Tq[ql] = T; cnt[ql] = 0; }
  }
  __syncthreads();
  const float T  = Tq[ql];
  const float Tm = T + fabsf(T) * 1e-6f + 1e-30f;

  for (int tile = 0; tile < SEG_N / KNN_TILE; ++tile) {
    __syncthreads();
    for (int u = tid; u < KNN_TILE; u += 256) {
      size_t g = (size_t)(s * SEG_N + tile * KNN_TILE + u);
      px[u] = xyz[g*3+0]; py[u] = xyz[g*3+1]; pz[u] = xyz[g*3+2];
    }
    __syncthreads();
    for (int i = 0; i < KNN_TILE / 16; ++i) {
      int c = i * 16 + j;
      float x = px[c], y = py[c], z = pz[c];
      float sp  = x*x + y*y + z*z;
      float dot = qx*x + qy*y + qz*z;
      float d2  = (sq + sp) - 2.0f * dot;
      if (d2 <= Tm) {
        int pos = atomicAdd(&cnt[ql], 1);
        if (pos < 24) { dbuf[ql][pos] = d2; cbuf[ql][pos] = tile * KNN_TILE + c; }
      }
    }
  }
  __syncthreads();

  if (j == 0) {
    int n = cnt[ql]; if (n > 24) n = 24;
    for (int r = 0; r < NSAMPLE; ++r) {
      float bv = 3.4e38f; int bc = 0, bp = -1;
      for (int e = 0; e < n; ++e) {
        float dv = dbuf[ql][e]; int cc = cbuf[ql][e];
        if (dv < bv || (dv == bv && cc < bc)) { bv = dv; bc = cc; bp = e; }
      }
      if (bp >= 0) dbuf[ql][bp] = 3.4e38f;
      knn[qg * NSAMPLE + r] = bc;
    }
  }
}

// ---------------------------------------------------------------------------
__global__ __launch_bounds__(128)
void gemm_kernel(const float* __restrict__ feat, const float* __restrict__ W,
                 const int* __restrict__ knn, float* __restrict__ out)
{
  __shared__ __align__(16) float f[NSAMPLE][CFEAT];
  __shared__ int kid[NSAMPLE];
  const int tid = threadIdx.x;
  const int q = blockIdx.x;
  const int s = q >> 11;
  if (tid < NSAMPLE) kid[tid] = knn[q * NSAMPLE + tid] & 8191;
  __syncthreads();
  for (int e = tid; e < NSAMPLE * CFEAT; e += 128) {
    int k = e >> 6, c = e & 63;
    f[k][c] = feat[(size_t)(s * SEG_N + kid[k]) * CFEAT + c];
  }
  float4 w[16];
  const float4* Wrow = (const float4*)(W + (size_t)tid * CFEAT);
  #pragma unroll
  for (int c4 = 0; c4 < 16; ++c4) w[c4] = Wrow[c4];
  __syncthreads();

  float m = -3.4e38f;
  #pragma unroll
  for (int k = 0; k < NSAMPLE; ++k) {
    float acc = 0.f;
    const float4* frow = (const float4*)&f[k][0];
    #pragma unroll
    for (int c4 = 0; c4 < 16; ++c4) {
      float4 fv = frow[c4];
      acc += fv.x * w[c4].x + fv.y * w[c4].y + fv.z * w[c4].z + fv.w * w[c4].w;
    }
    m = fmaxf(m, acc);
  }
  out[OUT_FEAT + (size_t)q * COUT + tid] = fmaxf(m, 0.f);
}

// ---------------------------------------------------------------------------
extern "C" void kernel_launch(void* const* d_in, const int* in_sizes, int n_in,
                              void* d_out, int out_size, void* d_ws, size_t ws_size,
                              hipStream_t stream)
{
  const float* xyz  = (const float*)d_in[0];
  const float* feat = (const float*)d_in[1];
  // d_in[2] = offset (segment sizes fixed by the problem)
  const float* vel  = (const float*)d_in[3];
  const float* W    = (const float*)d_in[4];
  float* out = (float*)d_out;
  char*  ws  = (char*)d_ws;
  u64* cand    = (u64*)(ws + WS_CAND);
  int* fps_idx = (int*)(ws + WS_FPS);
  int* knn     = (int*)(ws + WS_KNN);

  if (ws_size >= (size_t)WS_D2 + NSEG * D2_SEG8) {
    float* sq = (float*)(ws + WS_SQ);
    unsigned char* d2m = (unsigned char*)(ws + WS_D2);
    norm_kernel<<<(NSEG * SEG_N) / 256, 256, 0, stream>>>(xyz, feat, sq);
    gram_mfma_kernel<<<NSEG * 64 * 64, 256, 0, stream>>>(xyz, feat, sq, d2m);
    fps_fast8_kernel<<<NSEG, 1024, 0, stream>>>(d2m, fps_idx);
  } else {
    hipMemsetAsync(cand, 0, 512, stream);
    fps_kernel<<<NSEG * FPS_WGS_PER_SEG, FPS_THREADS, 0, stream>>>(
        xyz, feat, cand, fps_idx);
  }
  gather_kernel<<<M_TOTAL / 256, 256, 0, stream>>>(xyz, vel, fps_idx, out);
  knn_kernel<<<M_TOTAL / 16, 256, 0, stream>>>(xyz, out, knn);
  gemm_kernel<<<M_TOTAL, 128, 0, stream>>>(feat, W, knn, out);
}

// Round 17
// 1785.611 us; speedup vs baseline: 1.2723x; 1.2723x over previous
//
#include <hip/hip_runtime.h>
#include <hip/hip_fp16.h>

typedef unsigned long long u64;
typedef __attribute__((ext_vector_type(8))) short bf16x8;
typedef __attribute__((ext_vector_type(4))) float f32x4;

#define SEG_N     8192
#define NSEG      2
#define M_PER_SEG 2048
#define M_TOTAL   4096
#define CFEAT     64
#define COUT      128
#define NSAMPLE   16

#define FPS_WGS_PER_SEG 16
#define FPS_THREADS     512
#define FPS_WAVES       8
#define SLOT_STRIDE     16

// d_out layout (floats): new_xyz | new_feat | new_offset | new_vel
#define OUT_XYZ   0
#define OUT_FEAT  12288
#define OUT_OFF   536576
#define OUT_VEL   536578

// d_ws layout (bytes)
#define WS_CAND 0
#define WS_FPS  512
#define WS_KNN  16896
#define WS_SQ   (1<<19)
#define WS_D2   (1<<20)
#define D2_SEG8 ((size_t)SEG_N * SEG_N)       // 67 MB per segment (u8)

#define AG  __HIP_MEMORY_SCOPE_AGENT
#define RLX __ATOMIC_RELAXED

#define REP16(M) M(0) M(1) M(2) M(3) M(4) M(5) M(6) M(7) \
                 M(8) M(9) M(10) M(11) M(12) M(13) M(14) M(15)
#define REP16_EO(E,O) E(0) O(1) E(2) O(3) E(4) O(5) E(6) O(7) \
                      E(8) O(9) E(10) O(11) E(12) O(13) E(14) O(15)

__device__ __forceinline__ unsigned pk2(float a, float b) {
  __half2 h = __floats2half2_rn(a, b);
  unsigned u; __builtin_memcpy(&u, &h, 4); return u;
}
__device__ __forceinline__ float2 up2(unsigned u) {
  __half2 h; __builtin_memcpy(&h, &u, 4);
  return __half22float2(h);
}

template<int CTRL, int RM>
__device__ __forceinline__ unsigned dppmax(unsigned c) {
  int t = __builtin_amdgcn_update_dpp(0, (int)c, CTRL, RM, 0xF, true);
  unsigned u = (unsigned)t;
  return c > u ? c : u;
}

__device__ __forceinline__ short f2bf(float v) {
  return (short)((__float_as_uint(v) + 0x8000u) >> 16);   // RN-ish bf16
}

// ===========================================================================
// FAST PATH: u8 d^2 matrix via MFMA-bf16 gram; FPS = 512-thread low-sync.
// ===========================================================================

__global__ __launch_bounds__(256)
void norm_kernel(const float* __restrict__ xyz, const float* __restrict__ feat,
                 float* __restrict__ sq)
{
  int i = blockIdx.x * 256 + threadIdx.x;
  if (i >= NSEG * SEG_N) return;
  float a0 = xyz[(size_t)i*3+0], a1 = xyz[(size_t)i*3+1], a2 = xyz[(size_t)i*3+2];
  float acc = a0*a0 + a1*a1 + a2*a2;
  const float4* fr = (const float4*)(feat + (size_t)i * CFEAT);
  #pragma unroll
  for (int k = 0; k < 16; ++k) {
    float4 v = fr[k];
    acc += v.x*v.x + v.y*v.y + v.z*v.z + v.w*v.w;
  }
  sq[i] = acc;
}

// MFMA bf16 gram: 128q x 128p u8 d^2 tile per WG. K = 96 (xyz|feat|zeros).
#define GKS 104
__global__ __launch_bounds__(256)
void gram_mfma_kernel(const float* __restrict__ xyz, const float* __restrict__ feat,
                      const float* __restrict__ sq, unsigned char* __restrict__ d2m)
{
  __shared__ __align__(16) short Xq[128][GKS];
  __shared__ __align__(16) short Xp[128][GKS];
  __shared__ float sqs[128], sps[128];

  const int b   = blockIdx.x;
  const int s   = b >> 12;
  const int rem = b & 4095;
  const int tq  = rem >> 6;
  const int tp  = rem & 63;
  const int q0  = tq * 128, p0 = tp * 128;
  const int tid = threadIdx.x;
  unsigned char* d2seg = d2m + (size_t)s * D2_SEG8;

  for (int e = tid; e < 128 * 96; e += 256) {
    int r = e / 96, c = e - r * 96;
    size_t gq = (size_t)(s * SEG_N + q0 + r);
    size_t gp = (size_t)(s * SEG_N + p0 + r);
    float vq = 0.f, vp = 0.f;
    if (c < 3)        { vq = xyz[gq*3 + c];          vp = xyz[gp*3 + c]; }
    else if (c < 67)  { vq = feat[gq*CFEAT + (c-3)]; vp = feat[gp*CFEAT + (c-3)]; }
    Xq[r][c] = f2bf(vq);
    Xp[r][c] = f2bf(vp);
  }
  if (tid < 128)      sqs[tid] = sq[s * SEG_N + q0 + tid];
  else                sps[tid - 128] = sq[s * SEG_N + p0 + (tid - 128)];
  __syncthreads();

  const int lane = tid & 63;
  const int wv   = tid >> 6;
  const int wr   = wv >> 1, wc = wv & 1;
  const int lrow = lane & 15;
  const int kgr  = (lane >> 4) * 8;

  f32x4 acc[4][4];
  #pragma unroll
  for (int i = 0; i < 4; ++i)
    #pragma unroll
    for (int j = 0; j < 4; ++j) acc[i][j] = (f32x4){0.f,0.f,0.f,0.f};

  #pragma unroll
  for (int ch = 0; ch < 3; ++ch) {
    bf16x8 af[4], bf[4];
    #pragma unroll
    for (int i = 0; i < 4; ++i)
      af[i] = *(const bf16x8*)&Xq[wr*64 + i*16 + lrow][ch*32 + kgr];
    #pragma unroll
    for (int j = 0; j < 4; ++j)
      bf[j] = *(const bf16x8*)&Xp[wc*64 + j*16 + lrow][ch*32 + kgr];
    #pragma unroll
    for (int i = 0; i < 4; ++i)
      #pragma unroll
      for (int j = 0; j < 4; ++j)
        acc[i][j] = __builtin_amdgcn_mfma_f32_16x16x32_bf16(af[i], bf[j],
                                                            acc[i][j], 0, 0, 0);
  }
  __syncthreads();

  unsigned char* ob = (unsigned char*)&Xq[0][0];
  #pragma unroll
  for (int i = 0; i < 4; ++i) {
    #pragma unroll
    for (int j = 0; j < 4; ++j) {
      #pragma unroll
      for (int reg = 0; reg < 4; ++reg) {
        int r  = wr*64 + i*16 + (lane >> 4)*4 + reg;
        int cl = wc*64 + j*16 + (lane & 15);
        float d2 = sqs[r] + sps[cl] - 2.f * acc[i][j][reg];
        unsigned o;
        if (q0 + r == p0 + cl) o = 0u;
        else {
          d2 = fmaxf(d2, 0.f);
          o = __float2uint_rn(fminf(d2, 255.f));
        }
        ob[(r << 7) + cl] = (unsigned char)o;
      }
    }
  }
  __syncthreads();

  const unsigned* obu = (const unsigned*)ob;
  for (int e = tid; e < 4096; e += 256) {
    int r = e >> 5, cw = e & 31;
    *(unsigned*)&d2seg[((size_t)(q0 + r) << 13) + p0 + cw*4] = obu[e];
  }
}

// FPS from the u8 matrix: 512 threads x 16 points (one uint4 row-slice per
// thread). Halves the barrier width (8 waves) and the funnel (8 slots, 3 DPP)
// vs the 1024-thread version; selections are partition-invariant (same global
// packed-candidate max) -> bit-identical picks. No prefetch (R14/R16 both
// showed the issue-to-use distance is too short to hide HBM latency).
__global__ __launch_bounds__(512)
void fps_fast8_kernel(const unsigned char* __restrict__ d2m,
                      int* __restrict__ fps_idx)
{
  __shared__ unsigned wslot[2][8];

  const int tid  = threadIdx.x;
  const int lane = tid & 63;
  const int wv   = tid >> 6;                 // 0..7
  const int s    = blockIdx.x;
  const int p0   = tid * 16;
  const unsigned idx0 = 8191 - p0;           // inv-index of my point k=0
  const unsigned char* base_s = d2m + (size_t)s * D2_SEG8;

#define DECLD(k) unsigned Dv##k = 255u;
  REP16(DECLD)

  if (tid == 0) fps_idx[s * M_PER_SEG] = 0;
  int q = 0;

  for (int t = 1; t < M_PER_SEG; ++t) {
    uint4 w = *(const uint4*)(base_s + ((size_t)q << 13) + p0);
    Dv0  = min(Dv0,   w.x        & 255u);
    Dv1  = min(Dv1,  (w.x >>  8) & 255u);
    Dv2  = min(Dv2,  (w.x >> 16) & 255u);
    Dv3  = min(Dv3,   w.x >> 24);
    Dv4  = min(Dv4,   w.y        & 255u);
    Dv5  = min(Dv5,  (w.y >>  8) & 255u);
    Dv6  = min(Dv6,  (w.y >> 16) & 255u);
    Dv7  = min(Dv7,   w.y >> 24);
    Dv8  = min(Dv8,   w.z        & 255u);
    Dv9  = min(Dv9,  (w.z >>  8) & 255u);
    Dv10 = min(Dv10, (w.z >> 16) & 255u);
    Dv11 = min(Dv11,  w.z >> 24);
    Dv12 = min(Dv12,  w.w        & 255u);
    Dv13 = min(Dv13, (w.w >>  8) & 255u);
    Dv14 = min(Dv14, (w.w >> 16) & 255u);
    Dv15 = min(Dv15,  w.w >> 24);

    // packed candidates: dist<<13 | inv-idx  (ties -> lowest point index)
    unsigned c = (Dv0 << 13) | idx0;
    c = max(c, (Dv1  << 13) | (idx0 -  1u));
    c = max(c, (Dv2  << 13) | (idx0 -  2u));
    c = max(c, (Dv3  << 13) | (idx0 -  3u));
    c = max(c, (Dv4  << 13) | (idx0 -  4u));
    c = max(c, (Dv5  << 13) | (idx0 -  5u));
    c = max(c, (Dv6  << 13) | (idx0 -  6u));
    c = max(c, (Dv7  << 13) | (idx0 -  7u));
    c = max(c, (Dv8  << 13) | (idx0 -  8u));
    c = max(c, (Dv9  << 13) | (idx0 -  9u));
    c = max(c, (Dv10 << 13) | (idx0 - 10u));
    c = max(c, (Dv11 << 13) | (idx0 - 11u));
    c = max(c, (Dv12 << 13) | (idx0 - 12u));
    c = max(c, (Dv13 << 13) | (idx0 - 13u));
    c = max(c, (Dv14 << 13) | (idx0 - 14u));
    c = max(c, (Dv15 << 13) | (idx0 - 15u));

    // 64-lane DPP max reduce -> lane 63 (R13-proven sequence)
    c = dppmax<0x111, 0xF>(c);   // row_shr:1
    c = dppmax<0x112, 0xF>(c);   // row_shr:2
    c = dppmax<0x114, 0xF>(c);   // row_shr:4
    c = dppmax<0x118, 0xF>(c);   // row_shr:8
    c = dppmax<0x142, 0xA>(c);   // row_bcast:15 (rows 1,3)
    c = dppmax<0x143, 0xC>(c);   // row_bcast:31 (rows 2,3)
    unsigned wmax = (unsigned)__builtin_amdgcn_readlane((int)c, 63);

    if (lane == 0) wslot[t & 1][wv] = wmax;
    __syncthreads();                        // single (8-wave) barrier per step

    unsigned v = wslot[t & 1][lane & 7];
    v = dppmax<0x111, 0xF>(v);
    v = dppmax<0x112, 0xF>(v);
    v = dppmax<0x114, 0xF>(v);              // lane7 of each row = global max
    unsigned gmax = (unsigned)__builtin_amdgcn_readlane((int)v, 7);
    q = 8191 - (int)(gmax & 0x1FFFu);       // uniform (SGPR) -> saddr row load
    if (tid == 0) fps_idx[s * M_PER_SEG + t] = q;
  }
}

// ===========================================================================
// FALLBACK: distributed MALL-sync FPS, fp16-packed named registers.
// ===========================================================================
__global__ __attribute__((amdgpu_waves_per_eu(2, 2)))
__launch_bounds__(FPS_THREADS)
void fps_kernel(const float* __restrict__ xyz, const float* __restrict__ feat,
                u64* __restrict__ cand, int* __restrict__ fps_idx)
{
#pragma clang fp contract(off)
  __shared__ u64 wslot[FPS_WAVES];
  __shared__ int qidx_sh;

  const int tid  = threadIdx.x;
  const int lane = tid & 63;
  const int wv   = tid >> 6;
  const int s    = blockIdx.x >> 4;
  const int wg   = blockIdx.x & 15;
  const int pl   = wg * FPS_THREADS + tid;
  const size_t gr = (size_t)(s * SEG_N + pl);

  float px, py, pz;
#define DECLP(k) uint2 pp##k;
  REP16(DECLP)
  px = xyz[gr*3+0]; py = xyz[gr*3+1]; pz = xyz[gr*3+2];
  {
    const float4* fr = (const float4*)(feat + gr * CFEAT);
#define LOADP(k) { float4 v = fr[k]; pp##k.x = pk2(v.x, v.y); pp##k.y = pk2(v.z, v.w); }
    REP16(LOADP)
  }

  float qx, qy, qz;
#define DECLQ(k) float4 qf##k;
  REP16(DECLQ)
#define LOADQ1(k) qf##k = frq[k];
#define LOAD_Q(qb) { \
    qx = xyz[(qb)*3+0]; qy = xyz[(qb)*3+1]; qz = xyz[(qb)*3+2]; \
    const float4* frq = (const float4*)(feat + (qb) * CFEAT); \
    REP16(LOADQ1) }

  LOAD_Q((size_t)(s * SEG_N))
  if (tid == 0 && wg == 0) fps_idx[s * M_PER_SEG] = 0;

  float D = 1e10f;

  for (int t = 1; t < M_PER_SEG; ++t) {
    float r0=0.f, r1=0.f, r2=0.f, r3=0.f, r4=0.f, r5=0.f, r6=0.f, r7=0.f;
    {
      float tt;
      tt = px - qx; r0 += tt*tt;
      tt = py - qy; r1 += tt*tt;
      tt = pz - qz; r2 += tt*tt;
    }
#define DE(k) { float2 ab = up2(pp##k.x), cd = up2(pp##k.y); \
                float t0 = ab.x - qf##k.x; r3 += t0*t0; \
                float t1 = ab.y - qf##k.y; r4 += t1*t1; \
                float t2 = cd.x - qf##k.z; r5 += t2*t2; \
                float t3 = cd.y - qf##k.w; r6 += t3*t3; }
#define DO(k) { float2 ab = up2(pp##k.x), cd = up2(pp##k.y); \
                float t0 = ab.x - qf##k.x; r7 += t0*t0; \
                float t1 = ab.y - qf##k.y; r0 += t1*t1; \
                float t2 = cd.x - qf##k.z; r1 += t2*t2; \
                float t3 = cd.y - qf##k.w; r2 += t3*t3; }
    REP16_EO(DE, DO)
    float a = ((r0+r1)+(r2+r3)) + ((r4+r5)+(r6+r7));
    D = fminf(D, a);

    float bd = D; int bi = pl;
    #pragma unroll
    for (int off = 32; off >= 1; off >>= 1) {
      float od = __shfl_xor(bd, off);
      int   oi = __shfl_xor(bi, off);
      if (od > bd || (od == bd && oi < bi)) { bd = od; bi = oi; }
    }
    if (lane == 0)
      wslot[wv] = ((u64)__float_as_uint(bd) << 13) | (u64)(unsigned)(8191 - bi);
    __syncthreads();

    if (wv == 0) {
      u64 w = (lane < FPS_WAVES) ? wslot[lane] : 0ULL;
      #pragma unroll
      for (int off = 4; off >= 1; off >>= 1) {
        u64 o = __shfl_xor(w, off, 8);
        if (o > w) w = o;
      }
      u64* base = &cand[(((unsigned)t & 1u) * NSEG + s) * SLOT_STRIDE];
      if (lane == 0)
        __hip_atomic_store(&base[wg], ((u64)(unsigned)t << 45) | w, RLX, AG);

      u64 v = 0;
      if (lane < FPS_WGS_PER_SEG) {
        v = __hip_atomic_load(&base[lane], RLX, AG);
        while ((unsigned)(v >> 45) != (unsigned)t) {
          __builtin_amdgcn_s_sleep(1);
          v = __hip_atomic_load(&base[lane], RLX, AG);
        }
      }
      #pragma unroll
      for (int off = 8; off >= 1; off >>= 1) {
        u64 o = __shfl_xor(v, off, 16);
        if (o > v) v = o;
      }
      int qi = 8191 - (int)(v & 0x1FFFu);
      if (lane == 0) {
        qidx_sh = qi;
        if (wg == 0) fps_idx[s * M_PER_SEG + t] = qi;
      }
    }
    __syncthreads();

    LOAD_Q((size_t)(s * SEG_N + qidx_sh))
  }
}

// ---------------------------------------------------------------------------
__global__ void gather_kernel(const float* __restrict__ xyz, const float* __restrict__ vel,
                              const int* __restrict__ fps_idx, float* __restrict__ out)
{
  int i = blockIdx.x * 256 + threadIdx.x;
  if (i >= M_TOTAL) return;
  int s = i >> 11, r = i & 2047;
  int g = s * SEG_N + (fps_idx[s * M_PER_SEG + r] & 8191);
  out[OUT_XYZ + i*3 + 0] = xyz[(size_t)g*3 + 0];
  out[OUT_XYZ + i*3 + 1] = xyz[(size_t)g*3 + 1];
  out[OUT_XYZ + i*3 + 2] = xyz[(size_t)g*3 + 2];
  out[OUT_VEL + i*3 + 0] = vel[(size_t)g*3 + 0];
  out[OUT_VEL + i*3 + 1] = vel[(size_t)g*3 + 1];
  out[OUT_VEL + i*3 + 2] = vel[(size_t)g*3 + 2];
  if (i == 0) { out[OUT_OFF] = 2048.0f; out[OUT_OFF + 1] = 4096.0f; }
}

// ---------------------------------------------------------------------------
#define KNN_TILE 1024
__global__ __launch_bounds__(256)
void knn_kernel(const float* __restrict__ xyz, const float* __restrict__ out,
                int* __restrict__ knn)
{
  __shared__ float px[KNN_TILE], py[KNN_TILE], pz[KNN_TILE];
  __shared__ float ldK[16][16][16];
  __shared__ float Tq[16];
  __shared__ float dbuf[16][24];
  __shared__ int   cbuf[16][24];
  __shared__ int   cnt[16];

  const int tid = threadIdx.x;
  const int ql = tid >> 4, j = tid & 15;
  const int qg = blockIdx.x * 16 + ql;
  const int s  = qg >> 11;
  const float qx = out[OUT_XYZ + qg*3 + 0];
  const float qy = out[OUT_XYZ + qg*3 + 1];
  const float qz = out[OUT_XYZ + qg*3 + 2];
  const float sq = qx*qx + qy*qy + qz*qz;

  float K[16];
  #pragma unroll
  for (int r = 0; r < 16; ++r) K[r] = 3.4e38f;

  for (int tile = 0; tile < SEG_N / KNN_TILE; ++tile) {
    __syncthreads();
    for (int u = tid; u < KNN_TILE; u += 256) {
      size_t g = (size_t)(s * SEG_N + tile * KNN_TILE + u);
      px[u] = xyz[g*3+0]; py[u] = xyz[g*3+1]; pz[u] = xyz[g*3+2];
    }
    __syncthreads();
    #pragma unroll 4
    for (int i = 0; i < KNN_TILE / 16; ++i) {
      int c = i * 16 + j;
      float x = px[c], y = py[c], z = pz[c];
      float sp  = x*x + y*y + z*z;
      float dot = qx*x + qy*y + qz*z;
      float d2  = (sq + sp) - 2.0f * dot;
      #pragma unroll
      for (int r = 15; r >= 1; --r)
        K[r] = fminf(fmaxf(d2, K[r-1]), K[r]);
      K[0] = fminf(K[0], d2);
    }
  }
  #pragma unroll
  for (int r = 0; r < 16; ++r) ldK[ql][j][r] = K[r];
  __syncthreads();

  {
    int head = 0;
    float T = 3.4e38f;
    for (int r = 0; r < 16; ++r) {
      float val = (head < 16) ? ldK[ql][j][head] : 3.4e38f;
      float mv = val; int ml = j;
      #pragma unroll
      for (int off = 8; off >= 1; off >>= 1) {
        float ov = __shfl_xor(mv, off, 16);
        int   ol = __shfl_xor(ml, off, 16);
        if (ov < mv || (ov == mv && ol < ml)) { mv = ov; ml = ol; }
      }
      if (j == ml) head++;
      T = mv;
    }
    if (j == 0) { Tq[ql] = T; cnt[ql] = 0; }
  }
  __syncthreads();
  const float T  = Tq[ql];
  const float Tm = T + fabsf(T) * 1e-6f + 1e-30f;

  for (int tile = 0; tile < SEG_N / KNN_TILE; ++tile) {
    __syncthreads();
    for (int u = tid; u < KNN_TILE; u += 256) {
      size_t g = (size_t)(s * SEG_N + tile * KNN_TILE + u);
      px[u] = xyz[g*3+0]; py[u] = xyz[g*3+1]; pz[u] = xyz[g*3+2];
    }
    __syncthreads();
    for (int i = 0; i < KNN_TILE / 16; ++i) {
      int c = i * 16 + j;
      float x = px[c], y = py[c], z = pz[c];
      float sp  = x*x + y*y + z*z;
      float dot = qx*x + qy*y + qz*z;
      float d2  = (sq + sp) - 2.0f * dot;
      if (d2 <= Tm) {
        int pos = atomicAdd(&cnt[ql], 1);
        if (pos < 24) { dbuf[ql][pos] = d2; cbuf[ql][pos] = tile * KNN_TILE + c; }
      }
    }
  }
  __syncthreads();

  if (j == 0) {
    int n = cnt[ql]; if (n > 24) n = 24;
    for (int r = 0; r < NSAMPLE; ++r) {
      float bv = 3.4e38f; int bc = 0, bp = -1;
      for (int e = 0; e < n; ++e) {
        float dv = dbuf[ql][e]; int cc = cbuf[ql][e];
        if (dv < bv || (dv == bv && cc < bc)) { bv = dv; bc = cc; bp = e; }
      }
      if (bp >= 0) dbuf[ql][bp] = 3.4e38f;
      knn[qg * NSAMPLE + r] = bc;
    }
  }
}

// ---------------------------------------------------------------------------
__global__ __launch_bounds__(128)
void gemm_kernel(const float* __restrict__ feat, const float* __restrict__ W,
                 const int* __restrict__ knn, float* __restrict__ out)
{
  __shared__ __align__(16) float f[NSAMPLE][CFEAT];
  __shared__ int kid[NSAMPLE];
  const int tid = threadIdx.x;
  const int q = blockIdx.x;
  const int s = q >> 11;
  if (tid < NSAMPLE) kid[tid] = knn[q * NSAMPLE + tid] & 8191;
  __syncthreads();
  for (int e = tid; e < NSAMPLE * CFEAT; e += 128) {
    int k = e >> 6, c = e & 63;
    f[k][c] = feat[(size_t)(s * SEG_N + kid[k]) * CFEAT + c];
  }
  float4 w[16];
  const float4* Wrow = (const float4*)(W + (size_t)tid * CFEAT);
  #pragma unroll
  for (int c4 = 0; c4 < 16; ++c4) w[c4] = Wrow[c4];
  __syncthreads();

  float m = -3.4e38f;
  #pragma unroll
  for (int k = 0; k < NSAMPLE; ++k) {
    float acc = 0.f;
    const float4* frow = (const float4*)&f[k][0];
    #pragma unroll
    for (int c4 = 0; c4 < 16; ++c4) {
      float4 fv = frow[c4];
      acc += fv.x * w[c4].x + fv.y * w[c4].y + fv.z * w[c4].z + fv.w * w[c4].w;
    }
    m = fmaxf(m, acc);
  }
  out[OUT_FEAT + (size_t)q * COUT + tid] = fmaxf(m, 0.f);
}

// ---------------------------------------------------------------------------
extern "C" void kernel_launch(void* const* d_in, const int* in_sizes, int n_in,
                              void* d_out, int out_size, void* d_ws, size_t ws_size,
                              hipStream_t stream)
{
  const float* xyz  = (const float*)d_in[0];
  const float* feat = (const float*)d_in[1];
  // d_in[2] = offset (segment sizes fixed by the problem)
  const float* vel  = (const float*)d_in[3];
  const float* W    = (const float*)d_in[4];
  float* out = (float*)d_out;
  char*  ws  = (char*)d_ws;
  u64* cand    = (u64*)(ws + WS_CAND);
  int* fps_idx = (int*)(ws + WS_FPS);
  int* knn     = (int*)(ws + WS_KNN);

  if (ws_size >= (size_t)WS_D2 + NSEG * D2_SEG8) {
    float* sq = (float*)(ws + WS_SQ);
    unsigned char* d2m = (unsigned char*)(ws + WS_D2);
    norm_kernel<<<(NSEG * SEG_N) / 256, 256, 0, stream>>>(xyz, feat, sq);
    gram_mfma_kernel<<<NSEG * 64 * 64, 256, 0, stream>>>(xyz, feat, sq, d2m);
    fps_fast8_kernel<<<NSEG, 512, 0, stream>>>(d2m, fps_idx);
  } else {
    hipMemsetAsync(cand, 0, 512, stream);
    fps_kernel<<<NSEG * FPS_WGS_PER_SEG, FPS_THREADS, 0, stream>>>(
        xyz, feat, cand, fps_idx);
  }
  gather_kernel<<<M_TOTAL / 256, 256, 0, stream>>>(xyz, vel, fps_idx, out);
  knn_kernel<<<M_TOTAL / 16, 256, 0, stream>>>(xyz, out, knn);
  gemm_kernel<<<M_TOTAL, 128, 0, stream>>>(feat, W, knn, out);
}